// Round 14
// baseline (454.338 us; speedup 1.0000x reference)
//
#include <hip/hip_runtime.h>
#include <stdint.h>

typedef __attribute__((ext_vector_type(8))) short short8;
typedef __attribute__((ext_vector_type(8))) __bf16 bf16x8v;
typedef __attribute__((ext_vector_type(4))) float f32x4;

#define GLOBAL_AS __attribute__((address_space(1)))
#define LDS_AS __attribute__((address_space(3)))

__device__ __forceinline__ void gl2lds16(const void* g, void* l) {
  __builtin_amdgcn_global_load_lds((const GLOBAL_AS void*)g, (LDS_AS void*)l, 16, 0, 0);
}

__device__ __forceinline__ unsigned short f2bf(float x) {
  unsigned int u = __builtin_bit_cast(unsigned int, x);
  return (unsigned short)((u + 0x7fffu + ((u >> 16) & 1u)) >> 16);
}

__device__ __forceinline__ float bf2f(unsigned short u) {
  unsigned int v = (unsigned int)u << 16;
  return __builtin_bit_cast(float, v);
}

__device__ __forceinline__ unsigned cvtpk(float lo, float hi) {
  unsigned r;
  asm volatile("v_cvt_pk_bf16_f32 %0, %1, %2" : "=v"(r) : "v"(lo), "v"(hi));
  return r;
}

// native 2^x — single v_exp_f32
__device__ __forceinline__ float fexp2(float x) {
  float r;
  asm volatile("v_exp_f32 %0, %1" : "=v"(r) : "v"(x));
  return r;
}

__device__ __forceinline__ short8 ldv8(const unsigned short* p) {
  return *(const short8*)p;
}

// --- MFMA wrapper: SFINAE-hedged against builtin operand type (short8 vs v8bf16) ---
template <typename T>
__device__ __forceinline__ auto mfma_impl(T a, T b, f32x4 c, int)
    -> decltype(__builtin_amdgcn_mfma_f32_16x16x32_bf16(a, b, c, 0, 0, 0)) {
  return __builtin_amdgcn_mfma_f32_16x16x32_bf16(a, b, c, 0, 0, 0);
}
template <typename T>
__device__ __forceinline__ f32x4 mfma_impl(T a, T b, f32x4 c, long) {
  bf16x8v aa = __builtin_bit_cast(bf16x8v, a);
  bf16x8v bb = __builtin_bit_cast(bf16x8v, b);
  return __builtin_amdgcn_mfma_f32_16x16x32_bf16(aa, bb, c, 0, 0, 0);
}
__device__ __forceinline__ f32x4 mfma16(short8 a, short8 b, f32x4 c) {
  return mfma_impl(a, b, c, 0);
}

// ---------------- cast fp32 -> bf16 (vectorized) ----------------
__global__ __launch_bounds__(256) void cast_bf16_kernel(const float* __restrict__ X,
                                                        unsigned short* __restrict__ Y,
                                                        int n4) {
  int i = blockIdx.x * 256 + threadIdx.x;
  if (i >= n4) return;
  const float4 v = ((const float4*)X)[i];
  unsigned long long pk = (unsigned long long)f2bf(v.x)
                        | ((unsigned long long)f2bf(v.y) << 16)
                        | ((unsigned long long)f2bf(v.z) << 32)
                        | ((unsigned long long)f2bf(v.w) << 48);
  ((unsigned long long*)Y)[i] = pk;
}

// ---------------- transpose + cast: W[K][N] fp32 -> Wt[N][K] bf16 ----------------
__global__ __launch_bounds__(256) void transpose_cast_kernel(const float* __restrict__ W,
                                                             unsigned short* __restrict__ Wt,
                                                             int Kd, int Nd) {
  __shared__ unsigned short tile[32][33];
  const int n0 = blockIdx.x * 32, k0 = blockIdx.y * 32;
  const int tx = threadIdx.x & 31, ty = threadIdx.x >> 5;  // 32x8
  #pragma unroll
  for (int i = 0; i < 4; ++i)
    tile[ty + i * 8][tx] = f2bf(W[(long)(k0 + ty + i * 8) * Nd + n0 + tx]);
  __syncthreads();
  #pragma unroll
  for (int i = 0; i < 4; ++i)
    Wt[(long)(n0 + ty + i * 8) * Kd + k0 + tx] = tile[tx][ty + i * 8];
}

// ---------------- QKV GEMM: 256x128 tile, BK=32, 8 waves, 24 waves/CU ---------
// C[8192,3072] = A[8192,1024] @ Wt[3072,1024]^T + bias -> Q/K/Vt scatter.
// 512 thr = 8 waves (4M x 2N), per-wave 64x64 (acc[4][4], same body as 128² ver).
// Double-buffered LDS 48KB -> 3 blocks/CU = 24 waves/CU; grid 768 = ALL blocks
// resident in one generation (no tail). stage(t+1) at top, drain covered by
// the 6-waves/SIMD MFMA phase. XCD decode: A-panel 4MB pinned per XCD-pair L2.
__global__ __launch_bounds__(512, 6) void gemm_qkv(
    const unsigned short* __restrict__ A,   // [8192][1024] bf16
    const unsigned short* __restrict__ Wt,  // [3072][1024] bf16
    const float* __restrict__ bias,         // [3072]
    unsigned short* __restrict__ Qb,
    unsigned short* __restrict__ Kb,
    unsigned short* __restrict__ Vt) {
  constexpr int K = 1024, NT = 32;
  __shared__ __align__(16) unsigned short Asm[2][256 * 32];
  __shared__ __align__(16) unsigned short Bsm[2][128 * 32];
  const int tid = threadIdx.x;
  const int w = tid >> 6, l = tid & 63;

  const int bid = blockIdx.x;
  const int xcd = bid & 7, tt = bid >> 3;            // tt: 0..95
  const int xb = (xcd & 1) * 12 + tt % 12;           // 24 n-blocks
  const int yb = (xcd >> 1) * 8 + tt / 12;           // 32 m-blocks
  const int m0 = yb * 256, n0 = xb * 128;

  const int wr = (w >> 1) * 64, wc = (w & 1) * 64;
  const int laneRow = l & 15, laneG = l >> 4;

  const f32x4 z4 = {0.f, 0.f, 0.f, 0.f};
  f32x4 acc[4][4];
  #pragma unroll
  for (int m = 0; m < 4; ++m)
    #pragma unroll
    for (int n = 0; n < 4; ++n) acc[m][n] = z4;

  const int srow = tid >> 2;          // A: 0..127 (+128 on 2nd issue); B: 0..127
  const int scol = (tid & 3) * 8;
  const unsigned short* Ag = A + (long)(m0 + srow) * K + scol;
  const unsigned short* Bg = Wt + (long)(n0 + srow) * K + scol;

  const int aoff = (wr + laneRow) * 32 + laneG * 8;
  const int boff = (wc + laneRow) * 32 + laneG * 8;

  auto STAGE = [&](int buf, int kt) {
    gl2lds16(Ag + kt, &Asm[buf][w * 512]);
    gl2lds16(Ag + (long)128 * K + kt, &Asm[buf][4096 + w * 512]);
    gl2lds16(Bg + kt, &Bsm[buf][w * 512]);
  };

  STAGE(0, 0);
  asm volatile("s_waitcnt vmcnt(0)" ::: "memory");
  asm volatile("s_barrier" ::: "memory");

  int cur = 0;
  for (int t = 0; t < NT; ++t) {
    if (t + 1 < NT) STAGE(cur ^ 1, (t + 1) * 32);
    short8 af[4], bfr[4];
    #pragma unroll
    for (int m = 0; m < 4; ++m) af[m] = ldv8(&Asm[cur][aoff + m * 512]);
    #pragma unroll
    for (int n = 0; n < 4; ++n) bfr[n] = ldv8(&Bsm[cur][boff + n * 512]);
    __builtin_amdgcn_s_setprio(1);
    #pragma unroll
    for (int m = 0; m < 4; ++m)
      #pragma unroll
      for (int n = 0; n < 4; ++n)
        acc[m][n] = mfma16(af[m], bfr[n], acc[m][n]);
    __builtin_amdgcn_s_setprio(0);
    asm volatile("s_waitcnt vmcnt(0)" ::: "memory");
    asm volatile("s_barrier" ::: "memory");
    cur ^= 1;
  }

  if (n0 >= 2048) {
    // V: acc reg quad = 4 consecutive tokens at one e -> packed 8B stores
    #pragma unroll
    for (int m = 0; m < 4; ++m) {
      const int row_base = m0 + wr + m * 16 + laneG * 4;
      #pragma unroll
      for (int n = 0; n < 4; ++n) {
        const int col = n0 + wc + n * 16 + laneRow;
        const float bv = bias[col];
        const int d = col & 1023;
        const int h = d >> 6, e = d & 63;
        const int bb = row_base >> 11, s = row_base & 2047;
        unsigned long long pk = (unsigned long long)f2bf(acc[m][n][0] + bv)
                              | ((unsigned long long)f2bf(acc[m][n][1] + bv) << 16)
                              | ((unsigned long long)f2bf(acc[m][n][2] + bv) << 32)
                              | ((unsigned long long)f2bf(acc[m][n][3] + bv) << 48);
        *(unsigned long long*)(Vt + ((long)((bb * 16 + h) * 64 + e)) * 2048 + s) = pk;
      }
    }
    return;
  }

  // Q/K: per-wave LDS bounce (16x68 f32), coalesced 16B stores
  float* ep = (w < 6) ? ((float*)Asm + w * 1088) : ((float*)Bsm + (w - 6) * 1088);
  const int c0 = (l & 7) * 8;
  const int rrow = l >> 3;
  const int colg0 = n0 + wc + c0;
  float bv[8];
  #pragma unroll
  for (int j = 0; j < 8; ++j) bv[j] = bias[colg0 + j];
  unsigned short* Tqk = (colg0 >> 10) ? Kb : Qb;
  const int hh = (colg0 & 1023) >> 6, e0 = colg0 & 63;

  #pragma unroll
  for (int m = 0; m < 4; ++m) {
    asm volatile("s_waitcnt lgkmcnt(0)" ::: "memory");
    #pragma unroll
    for (int n = 0; n < 4; ++n)
      #pragma unroll
      for (int r = 0; r < 4; ++r)
        ep[(laneG * 4 + r) * 68 + n * 16 + laneRow] = acc[m][n][r];
    asm volatile("s_waitcnt lgkmcnt(0)" ::: "memory");
    #pragma unroll
    for (int j = 0; j < 2; ++j) {
      const int row = rrow + j * 8;
      f32x4 va = *(const f32x4*)&ep[row * 68 + c0];
      f32x4 vb = *(const f32x4*)&ep[row * 68 + c0 + 4];
      va[0] += bv[0]; va[1] += bv[1]; va[2] += bv[2]; va[3] += bv[3];
      vb[0] += bv[4]; vb[1] += bv[5]; vb[2] += bv[6]; vb[3] += bv[7];
      const int row_g = m0 + wr + m * 16 + row;
      uint4 pk;
      pk.x = cvtpk(va[0], va[1]);
      pk.y = cvtpk(va[2], va[3]);
      pk.z = cvtpk(vb[0], vb[1]);
      pk.w = cvtpk(vb[2], vb[3]);
      const int bb = row_g >> 11, s = row_g & 2047;
      *(uint4*)(Tqk + ((long)(bb * 16 + hh) * 2048 + s) * 64 + e0) = pk;
    }
  }
}

// ---------------- proj GEMM: 128x128, triple-buffered counted vmcnt(4) -------
__global__ __launch_bounds__(256, 3) void gemm_proj(
    const unsigned short* __restrict__ A,   // [M][K] bf16
    const unsigned short* __restrict__ Wt,  // [N][K] bf16
    const float* __restrict__ bias,         // [N]
    float* __restrict__ Cout,
    int M, int N, int K) {
  __shared__ __align__(16) unsigned short Asm[3][128 * 32];
  __shared__ __align__(16) unsigned short Bsm[3][128 * 32];
  const int tid = threadIdx.x;
  const int w = tid >> 6, l = tid & 63;

  const int bid = blockIdx.x;
  const int xcd = bid & 7, tt = bid >> 3;
  const int xb = tt & 7;
  const int yb = xcd * 8 + (tt >> 3);
  const int m0 = yb * 128, n0 = xb * 128;

  const int wr = (w >> 1) * 64, wc = (w & 1) * 64;
  const int laneRow = l & 15, laneG = l >> 4;

  const f32x4 z4 = {0.f, 0.f, 0.f, 0.f};
  f32x4 acc[4][4];
  #pragma unroll
  for (int m = 0; m < 4; ++m)
    #pragma unroll
    for (int n = 0; n < 4; ++n) acc[m][n] = z4;

  const int srow = tid >> 2;
  const int scol = (tid & 3) * 8;
  const unsigned short* Ag = A + (long)(m0 + srow) * K + scol;
  const unsigned short* Bg = Wt + (long)(n0 + srow) * K + scol;

  const int aoff = (wr + laneRow) * 32 + laneG * 8;
  const int boff = (wc + laneRow) * 32 + laneG * 8;

  auto STAGE = [&](int buf, int kt) {
    gl2lds16(Ag + kt, &Asm[buf][w * 512]);
    gl2lds16(Ag + (long)64 * K + kt, &Asm[buf][2048 + w * 512]);
    gl2lds16(Bg + kt, &Bsm[buf][w * 512]);
    gl2lds16(Bg + (long)64 * K + kt, &Bsm[buf][2048 + w * 512]);
  };

  const int NT = K >> 5;
  STAGE(0, 0);
  STAGE(1, 32);
  asm volatile("s_waitcnt vmcnt(4)" ::: "memory");
  asm volatile("s_barrier" ::: "memory");

  int cur = 0, sb = 2;
  for (int t = 0; t < NT; ++t) {
    if (t + 2 < NT) STAGE(sb, (t + 2) * 32);
    short8 af[4], bfr[4];
    #pragma unroll
    for (int m = 0; m < 4; ++m) af[m] = ldv8(&Asm[cur][aoff + m * 512]);
    #pragma unroll
    for (int n = 0; n < 4; ++n) bfr[n] = ldv8(&Bsm[cur][boff + n * 512]);
    __builtin_amdgcn_s_setprio(1);
    #pragma unroll
    for (int m = 0; m < 4; ++m)
      #pragma unroll
      for (int n = 0; n < 4; ++n)
        acc[m][n] = mfma16(af[m], bfr[n], acc[m][n]);
    __builtin_amdgcn_s_setprio(0);
    if (t + 2 < NT) {
      asm volatile("s_waitcnt vmcnt(4)" ::: "memory");
    } else {
      asm volatile("s_waitcnt vmcnt(0)" ::: "memory");
    }
    asm volatile("s_barrier" ::: "memory");
    cur = (cur == 2) ? 0 : cur + 1;
    sb = (sb == 2) ? 0 : sb + 1;
  }

  // LDS-bounce epilogue -> coalesced f32x4 stores
  float* ep = (float*)&Asm[0][0] + w * 1088;
  const int c0 = (l & 7) * 8;
  const int rrow = l >> 3;
  const int colg0 = n0 + wc + c0;
  float bv[8];
  #pragma unroll
  for (int j = 0; j < 8; ++j) bv[j] = bias[colg0 + j];

  #pragma unroll
  for (int m = 0; m < 4; ++m) {
    asm volatile("s_waitcnt lgkmcnt(0)" ::: "memory");
    #pragma unroll
    for (int n = 0; n < 4; ++n)
      #pragma unroll
      for (int r = 0; r < 4; ++r)
        ep[(laneG * 4 + r) * 68 + n * 16 + laneRow] = acc[m][n][r];
    asm volatile("s_waitcnt lgkmcnt(0)" ::: "memory");
    #pragma unroll
    for (int j = 0; j < 2; ++j) {
      const int row = rrow + j * 8;
      f32x4 va = *(const f32x4*)&ep[row * 68 + c0];
      f32x4 vb = *(const f32x4*)&ep[row * 68 + c0 + 4];
      va[0] += bv[0]; va[1] += bv[1]; va[2] += bv[2]; va[3] += bv[3];
      vb[0] += bv[4]; vb[1] += bv[5]; vb[2] += bv[6]; vb[3] += bv[7];
      const int row_g = m0 + wr + m * 16 + row;
      *(f32x4*)&Cout[(long)row_g * N + colg0] = va;
      *(f32x4*)&Cout[(long)row_g * N + colg0 + 4] = vb;
    }
  }
}

// ---------------- flash attention (causal), bf16 MFMA ----------------
// QBLK=128, 8 waves. Paired tiles px/(15-px), XCD-aware head grouping.
// SWAPPED QK^T -> S^T per lane; P via cvt_pk + b64 writes; no max-shift;
// P = 2^S via single v_exp_f32. Rowsum via mfma(P, ones).
// TRIPLE-buffered K/V with counted vmcnt(2).
__global__ __launch_bounds__(512) void attn_kernel(
    const unsigned short* __restrict__ Qb,   // [B*H][2048][64]
    const unsigned short* __restrict__ Kb,   // [B*H][2048][64]
    const unsigned short* __restrict__ Vt,   // [B*H][64][2048]
    unsigned short* __restrict__ Ao) {       // [B*2048][1024]
  __shared__ __align__(16) unsigned short Ksm[3][64 * 64];
  __shared__ __align__(16) unsigned short Vsm[3][64 * 64];
  __shared__ __align__(16) unsigned short Psm[8][16][72];

  const int tid = threadIdx.x;
  const int w = tid >> 6, l = tid & 63;
  const int bid = blockIdx.x;
  const int px = bid >> 6;                              // 0..7
  const int y = ((bid & 7) << 3) | ((bid >> 3) & 7);    // same-XCD head grouping
  const int laneRow = l & 15, g = l >> 4;
  const unsigned short* Qh = Qb + (long)y * (2048 * 64);
  const unsigned short* Kh = Kb + (long)y * (2048 * 64);
  const unsigned short* Vh = Vt + (long)y * (64 * 2048);

  const int srow = tid >> 3;
  const int sxor = ((tid & 7) ^ (srow & 7)) * 8;
  const int b = y >> 4, h = y & 15;
  const f32x4 z4 = {0.f, 0.f, 0.f, 0.f};
  short8 ones8;
  #pragma unroll
  for (int j = 0; j < 8; ++j) ones8[j] = (short)0x3F80;

  auto STAGE = [&](int buf, int kt) {
    gl2lds16(Kh + (long)kt * 4096 + srow * 64 + sxor, &Ksm[buf][w * 512]);
    gl2lds16(Vh + kt * 64 + (long)srow * 2048 + sxor, &Vsm[buf][w * 512]);
  };

  for (int pass = 0; pass < 2; ++pass) {
    const int x = pass ? (15 - px) : px;
    const int q0 = x * 128;
    const int qlo = w * 16;

    const float QS = 0.18033688011112042f;
    short8 qf[2];
    {
      short8 r0 = ldv8(Qh + (q0 + qlo + laneRow) * 64 + g * 8);
      short8 r1 = ldv8(Qh + (q0 + qlo + laneRow) * 64 + 32 + g * 8);
      #pragma unroll
      for (int j = 0; j < 8; ++j) {
        qf[0][j] = (short)f2bf(bf2f((unsigned short)r0[j]) * QS);
        qf[1][j] = (short)f2bf(bf2f((unsigned short)r1[j]) * QS);
      }
    }

    float lr[4] = {0.f, 0.f, 0.f, 0.f};
    f32x4 o[4];
    #pragma unroll
    for (int i = 0; i < 4; ++i) o[i] = z4;

    const int nkt = 2 * x + 2;  // always >= 2
    STAGE(0, 0);
    STAGE(1, 1);
    asm volatile("s_waitcnt vmcnt(2)" ::: "memory");
    __builtin_amdgcn_s_barrier();

    int cur = 0, sb = 2;
    for (int kt = 0; kt < nkt; ++kt) {
      if (kt + 2 < nkt) STAGE(sb, kt + 2);

      const int keybase = kt * 64 - q0;
      const bool fullskip = keybase > qlo + 15;

      if (!fullskip) {
        f32x4 sc[4];
        __builtin_amdgcn_s_setprio(1);
        #pragma unroll
        for (int n = 0; n < 4; ++n) {
          const int krow = n * 16 + laneRow;
          short8 b0 = ldv8(&Ksm[cur][krow * 64 + ((g ^ (krow & 7)) * 8)]);
          short8 b1 = ldv8(&Ksm[cur][krow * 64 + (((g + 4) ^ (krow & 7)) * 8)]);
          f32x4 a = mfma16(b0, qf[0], z4);
          sc[n] = mfma16(b1, qf[1], a);
        }
        __builtin_amdgcn_s_setprio(0);

        if (keybase + 63 > qlo) {
          #pragma unroll
          for (int n = 0; n < 4; ++n) {
            const int keyb = keybase + n * 16 + g * 4;
            #pragma unroll
            for (int r = 0; r < 4; ++r)
              if (keyb + r > qlo + laneRow) sc[n][r] = -1e9f;
          }
        }

        #pragma unroll
        for (int n = 0; n < 4; ++n)
          #pragma unroll
          for (int r = 0; r < 4; ++r)
            sc[n][r] = fexp2(sc[n][r]);

        #pragma unroll
        for (int n = 0; n < 4; ++n) {
          uint2 pk;
          pk.x = cvtpk(sc[n][0], sc[n][1]);
          pk.y = cvtpk(sc[n][2], sc[n][3]);
          *(uint2*)&Psm[w][laneRow][n * 16 + g * 4] = pk;
        }
        asm volatile("s_waitcnt lgkmcnt(0)" ::: "memory");

        f32x4 rs = z4;
        #pragma unroll
        for (int kk = 0; kk < 2; ++kk) {
          short8 pf = ldv8(&Psm[w][laneRow][kk * 32 + g * 8]);
          __builtin_amdgcn_s_setprio(1);
          #pragma unroll
          for (int n2 = 0; n2 < 4; ++n2) {
            const int vrow = n2 * 16 + laneRow;
            short8 vf = ldv8(&Vsm[cur][vrow * 64 + (((g + kk * 4) ^ (vrow & 7)) * 8)]);
            o[n2] = mfma16(pf, vf, o[n2]);
          }
          rs = mfma16(pf, ones8, rs);
          __builtin_amdgcn_s_setprio(0);
        }
        #pragma unroll
        for (int r = 0; r < 4; ++r) lr[r] += rs[r];
      }

      if (kt + 2 < nkt) {
        asm volatile("s_waitcnt vmcnt(2)" ::: "memory");
      } else {
        asm volatile("s_waitcnt vmcnt(0)" ::: "memory");
      }
      __builtin_amdgcn_s_barrier();
      cur = (cur == 2) ? 0 : cur + 1;
      sb = (sb == 2) ? 0 : sb + 1;
    }

    #pragma unroll
    for (int n2 = 0; n2 < 4; ++n2) {
      #pragma unroll
      for (int r = 0; r < 4; ++r) {
        float v = o[n2][r] / lr[r];
        long row = (long)b * 2048 + q0 + qlo + g * 4 + r;
        Ao[row * 1024 + h * 64 + n2 * 16 + laneRow] = f2bf(v);
      }
    }
  }
}

// ---------------- launch ----------------
extern "C" void kernel_launch(void* const* d_in, const int* in_sizes, int n_in,
                              void* d_out, int out_size, void* d_ws, size_t ws_size,
                              hipStream_t stream) {
  const float* hs = (const float*)d_in[0];      // [4,2048,1024]
  const float* W_attn = (const float*)d_in[1];  // [1024,3072]
  const float* b_attn = (const float*)d_in[2];  // [3072]
  const float* W_proj = (const float*)d_in[3];  // [1024,1024]
  const float* b_proj = (const float*)d_in[4];  // [1024]
  float* out = (float*)d_out;

  const size_t SZ_HS = 16777216;  // 8192*1024*2
  const size_t SZ_WA = 6291456;   // 3072*1024*2
  const size_t SZ_WP = 2097152;   // 1024*1024*2
  const size_t SZ_T = 16777216;   // Q / K / Vt / Ao each
  if (ws_size < SZ_HS + SZ_WA + SZ_WP + 4 * SZ_T) return;

  char* p = (char*)d_ws;
  unsigned short* hs_bf = (unsigned short*)p; p += SZ_HS;
  unsigned short* WtA = (unsigned short*)p;   p += SZ_WA;
  unsigned short* WtP = (unsigned short*)p;   p += SZ_WP;
  unsigned short* Qb = (unsigned short*)p;    p += SZ_T;
  unsigned short* Kb = (unsigned short*)p;    p += SZ_T;
  unsigned short* Vt = (unsigned short*)p;    p += SZ_T;
  unsigned short* Ao = (unsigned short*)p;    p += SZ_T;

  cast_bf16_kernel<<<8192, 256, 0, stream>>>(hs, hs_bf, 8192 * 1024 / 4);
  transpose_cast_kernel<<<dim3(96, 32), 256, 0, stream>>>(W_attn, WtA, 1024, 3072);
  transpose_cast_kernel<<<dim3(32, 32), 256, 0, stream>>>(W_proj, WtP, 1024, 1024);
  gemm_qkv<<<768, 512, 0, stream>>>(hs_bf, WtA, b_attn, Qb, Kb, Vt);
  attn_kernel<<<512, 512, 0, stream>>>(Qb, Kb, Vt, Ao);
  gemm_proj<<<512, 256, 0, stream>>>(Ao, WtP, b_proj, out, 8192, 1024, 1024);
}

// Round 15
// 172.452 us; speedup vs baseline: 2.6346x; 2.6346x over previous
//
#include <hip/hip_runtime.h>
#include <stdint.h>

typedef __attribute__((ext_vector_type(8))) short short8;
typedef __attribute__((ext_vector_type(8))) __bf16 bf16x8v;
typedef __attribute__((ext_vector_type(4))) float f32x4;

#define GLOBAL_AS __attribute__((address_space(1)))
#define LDS_AS __attribute__((address_space(3)))

__device__ __forceinline__ void gl2lds16(const void* g, void* l) {
  __builtin_amdgcn_global_load_lds((const GLOBAL_AS void*)g, (LDS_AS void*)l, 16, 0, 0);
}

__device__ __forceinline__ unsigned short f2bf(float x) {
  unsigned int u = __builtin_bit_cast(unsigned int, x);
  return (unsigned short)((u + 0x7fffu + ((u >> 16) & 1u)) >> 16);
}

__device__ __forceinline__ float bf2f(unsigned short u) {
  unsigned int v = (unsigned int)u << 16;
  return __builtin_bit_cast(float, v);
}

__device__ __forceinline__ unsigned cvtpk(float lo, float hi) {
  unsigned r;
  asm volatile("v_cvt_pk_bf16_f32 %0, %1, %2" : "=v"(r) : "v"(lo), "v"(hi));
  return r;
}

// native 2^x — single v_exp_f32
__device__ __forceinline__ float fexp2(float x) {
  float r;
  asm volatile("v_exp_f32 %0, %1" : "=v"(r) : "v"(x));
  return r;
}

__device__ __forceinline__ short8 ldv8(const unsigned short* p) {
  return *(const short8*)p;
}

// --- MFMA wrapper: SFINAE-hedged against builtin operand type (short8 vs v8bf16) ---
template <typename T>
__device__ __forceinline__ auto mfma_impl(T a, T b, f32x4 c, int)
    -> decltype(__builtin_amdgcn_mfma_f32_16x16x32_bf16(a, b, c, 0, 0, 0)) {
  return __builtin_amdgcn_mfma_f32_16x16x32_bf16(a, b, c, 0, 0, 0);
}
template <typename T>
__device__ __forceinline__ f32x4 mfma_impl(T a, T b, f32x4 c, long) {
  bf16x8v aa = __builtin_bit_cast(bf16x8v, a);
  bf16x8v bb = __builtin_bit_cast(bf16x8v, b);
  return __builtin_amdgcn_mfma_f32_16x16x32_bf16(aa, bb, c, 0, 0, 0);
}
__device__ __forceinline__ f32x4 mfma16(short8 a, short8 b, f32x4 c) {
  return mfma_impl(a, b, c, 0);
}

// ---------------- cast fp32 -> bf16 (vectorized) ----------------
__global__ __launch_bounds__(256) void cast_bf16_kernel(const float* __restrict__ X,
                                                        unsigned short* __restrict__ Y,
                                                        int n4) {
  int i = blockIdx.x * 256 + threadIdx.x;
  if (i >= n4) return;
  const float4 v = ((const float4*)X)[i];
  unsigned long long pk = (unsigned long long)f2bf(v.x)
                        | ((unsigned long long)f2bf(v.y) << 16)
                        | ((unsigned long long)f2bf(v.z) << 32)
                        | ((unsigned long long)f2bf(v.w) << 48);
  ((unsigned long long*)Y)[i] = pk;
}

// ---------------- transpose + cast: W[K][N] fp32 -> Wt[N][K] bf16 ----------------
__global__ __launch_bounds__(256) void transpose_cast_kernel(const float* __restrict__ W,
                                                             unsigned short* __restrict__ Wt,
                                                             int Kd, int Nd) {
  __shared__ unsigned short tile[32][33];
  const int n0 = blockIdx.x * 32, k0 = blockIdx.y * 32;
  const int tx = threadIdx.x & 31, ty = threadIdx.x >> 5;  // 32x8
  #pragma unroll
  for (int i = 0; i < 4; ++i)
    tile[ty + i * 8][tx] = f2bf(W[(long)(k0 + ty + i * 8) * Nd + n0 + tx]);
  __syncthreads();
  #pragma unroll
  for (int i = 0; i < 4; ++i)
    Wt[(long)(n0 + ty + i * 8) * Kd + k0 + tx] = tile[tx][ty + i * 8];
}

// ---------------- GEMM: C[M,N] = A[M,K] @ Wt[N,K]^T + bias ----------------
// 128x128 tile, BK=32. A TRIPLE-buffered (stage t+2), B DOUBLE-buffered
// (stage t+1; L2-hot, latency covered by compute). LDS 40KB -> 4 blocks/CU
// (16 waves/CU), VGPR ~68 under the 128 cap of launch_bounds(256,4).
// Boundary vmcnt(2): FIFO [A(t+1),B(t+1),A(t+2)] -> drains A/B(t+1),
// keeps A(t+2) in flight (counted, never drain-to-0 mid-loop).
// XCD-aware 1D block decode. MODE 0: QKV scatter; MODE 1: fp32 out.
template <int MODE>
__global__ __launch_bounds__(256, 4) void gemm_kernel(
    const unsigned short* __restrict__ A,   // [M][K] bf16
    const unsigned short* __restrict__ Wt,  // [N][K] bf16
    const float* __restrict__ bias,         // [N]
    float* __restrict__ Cout,               // MODE1
    unsigned short* __restrict__ Qb,
    unsigned short* __restrict__ Kb,
    unsigned short* __restrict__ Vt,
    int M, int N, int K) {
  __shared__ __align__(16) unsigned short Asm[3][128 * 32];
  __shared__ __align__(16) unsigned short Bsm[2][128 * 32];
  const int tid = threadIdx.x;
  const int w = tid >> 6, l = tid & 63;

  const int bid = blockIdx.x;
  const int xcd = bid & 7, tt = bid >> 3;
  int xb, yb;
  if (MODE == 0) {
    xb = (xcd & 1) * 12 + tt % 12;   // 24 n-blocks
    yb = (xcd >> 1) * 16 + tt / 12;  // 64 m-blocks
  } else {
    xb = tt & 7;                     // 8 n-blocks
    yb = xcd * 8 + (tt >> 3);        // 64 m-blocks
  }
  const int m0 = yb * 128, n0 = xb * 128;

  const int wr = (w >> 1) * 64, wc = (w & 1) * 64;
  const int laneRow = l & 15, laneG = l >> 4;

  const f32x4 z4 = {0.f, 0.f, 0.f, 0.f};
  f32x4 acc[4][4];
  #pragma unroll
  for (int m = 0; m < 4; ++m)
    #pragma unroll
    for (int n = 0; n < 4; ++n) acc[m][n] = z4;

  const int srow = tid >> 2;
  const int scol = (tid & 3) * 8;
  const unsigned short* Ag = A + (long)(m0 + srow) * K + scol;
  const unsigned short* Bg = Wt + (long)(n0 + srow) * K + scol;

  const int aoff = (wr + laneRow) * 32 + laneG * 8;
  const int boff = (wc + laneRow) * 32 + laneG * 8;

  auto STAGE_A = [&](int buf, int kt) {
    gl2lds16(Ag + kt, &Asm[buf][w * 512]);
    gl2lds16(Ag + (long)64 * K + kt, &Asm[buf][2048 + w * 512]);
  };
  auto STAGE_B = [&](int buf, int kt) {
    gl2lds16(Bg + kt, &Bsm[buf][w * 512]);
    gl2lds16(Bg + (long)64 * K + kt, &Bsm[buf][2048 + w * 512]);
  };

  const int NT = K >> 5;
  STAGE_A(0, 0);
  STAGE_B(0, 0);
  STAGE_A(1, 32);
  asm volatile("s_waitcnt vmcnt(2)" ::: "memory");  // A0,B0 ready; A1 in flight
  asm volatile("s_barrier" ::: "memory");

  int cura = 0, sba = 2;
  for (int t = 0; t < NT; ++t) {
    const int curb = t & 1;
    if (t + 1 < NT) STAGE_B(curb ^ 1, (t + 1) * 32);
    if (t + 2 < NT) STAGE_A(sba, (t + 2) * 32);
    short8 af[4], bfr[4];
    #pragma unroll
    for (int m = 0; m < 4; ++m) af[m] = ldv8(&Asm[cura][aoff + m * 512]);
    #pragma unroll
    for (int n = 0; n < 4; ++n) bfr[n] = ldv8(&Bsm[curb][boff + n * 512]);
    __builtin_amdgcn_s_setprio(1);
    #pragma unroll
    for (int m = 0; m < 4; ++m)
      #pragma unroll
      for (int n = 0; n < 4; ++n)
        acc[m][n] = mfma16(af[m], bfr[n], acc[m][n]);
    __builtin_amdgcn_s_setprio(0);
    // drain A(t+1)+B(t+1); keep A(t+2) in flight
    if (t + 2 < NT) {
      asm volatile("s_waitcnt vmcnt(2)" ::: "memory");
    } else {
      asm volatile("s_waitcnt vmcnt(0)" ::: "memory");
    }
    asm volatile("s_barrier" ::: "memory");
    cura = (cura == 2) ? 0 : cura + 1;
    sba = (sba == 2) ? 0 : sba + 1;
  }

  if (MODE == 0 && n0 >= 2048) {
    #pragma unroll
    for (int m = 0; m < 4; ++m) {
      const int row_base = m0 + wr + m * 16 + laneG * 4;
      #pragma unroll
      for (int n = 0; n < 4; ++n) {
        const int col = n0 + wc + n * 16 + laneRow;
        const float bv = bias[col];
        const int d = col & 1023;
        const int h = d >> 6, e = d & 63;
        const int bb = row_base >> 11, s = row_base & 2047;
        unsigned long long pk = (unsigned long long)f2bf(acc[m][n][0] + bv)
                              | ((unsigned long long)f2bf(acc[m][n][1] + bv) << 16)
                              | ((unsigned long long)f2bf(acc[m][n][2] + bv) << 32)
                              | ((unsigned long long)f2bf(acc[m][n][3] + bv) << 48);
        *(unsigned long long*)(Vt + ((long)((bb * 16 + h) * 64 + e)) * 2048 + s) = pk;
      }
    }
    return;
  }

  // LDS-bounce epilogue: per-wave 16x68 f32 region, coalesced 16B stores
  float* ep = (float*)&Asm[0][0] + w * 1088;
  const int c0 = (l & 7) * 8;
  const int rrow = l >> 3;
  const int colg0 = n0 + wc + c0;
  float bv[8];
  #pragma unroll
  for (int j = 0; j < 8; ++j) bv[j] = bias[colg0 + j];
  unsigned short* Tqk = (colg0 >> 10) ? Kb : Qb;
  const int hh = (colg0 & 1023) >> 6, e0 = colg0 & 63;

  #pragma unroll
  for (int m = 0; m < 4; ++m) {
    asm volatile("s_waitcnt lgkmcnt(0)" ::: "memory");
    #pragma unroll
    for (int n = 0; n < 4; ++n)
      #pragma unroll
      for (int r = 0; r < 4; ++r)
        ep[(laneG * 4 + r) * 68 + n * 16 + laneRow] = acc[m][n][r];
    asm volatile("s_waitcnt lgkmcnt(0)" ::: "memory");
    #pragma unroll
    for (int j = 0; j < 2; ++j) {
      const int row = rrow + j * 8;
      f32x4 va = *(const f32x4*)&ep[row * 68 + c0];
      f32x4 vb = *(const f32x4*)&ep[row * 68 + c0 + 4];
      va[0] += bv[0]; va[1] += bv[1]; va[2] += bv[2]; va[3] += bv[3];
      vb[0] += bv[4]; vb[1] += bv[5]; vb[2] += bv[6]; vb[3] += bv[7];
      const int row_g = m0 + wr + m * 16 + row;
      if (MODE == 1) {
        *(f32x4*)&Cout[(long)row_g * N + colg0] = va;
        *(f32x4*)&Cout[(long)row_g * N + colg0 + 4] = vb;
      } else {
        uint4 pk;
        pk.x = cvtpk(va[0], va[1]);
        pk.y = cvtpk(va[2], va[3]);
        pk.z = cvtpk(vb[0], vb[1]);
        pk.w = cvtpk(vb[2], vb[3]);
        const int bb = row_g >> 11, s = row_g & 2047;
        *(uint4*)(Tqk + ((long)(bb * 16 + hh) * 2048 + s) * 64 + e0) = pk;
      }
    }
  }
}

// ---------------- flash attention (causal), bf16 MFMA ----------------
// QBLK=128, 8 waves. Paired tiles px/(15-px), XCD-aware head grouping.
// SWAPPED QK^T -> S^T per lane; P via cvt_pk + b64 writes; no max-shift;
// P = 2^S via single v_exp_f32. Rowsum via mfma(P, ones).
// TRIPLE-buffered K/V with counted vmcnt(2).
__global__ __launch_bounds__(512) void attn_kernel(
    const unsigned short* __restrict__ Qb,   // [B*H][2048][64]
    const unsigned short* __restrict__ Kb,   // [B*H][2048][64]
    const unsigned short* __restrict__ Vt,   // [B*H][64][2048]
    unsigned short* __restrict__ Ao) {       // [B*2048][1024]
  __shared__ __align__(16) unsigned short Ksm[3][64 * 64];
  __shared__ __align__(16) unsigned short Vsm[3][64 * 64];
  __shared__ __align__(16) unsigned short Psm[8][16][72];

  const int tid = threadIdx.x;
  const int w = tid >> 6, l = tid & 63;
  const int bid = blockIdx.x;
  const int px = bid >> 6;                              // 0..7
  const int y = ((bid & 7) << 3) | ((bid >> 3) & 7);    // same-XCD head grouping
  const int laneRow = l & 15, g = l >> 4;
  const unsigned short* Qh = Qb + (long)y * (2048 * 64);
  const unsigned short* Kh = Kb + (long)y * (2048 * 64);
  const unsigned short* Vh = Vt + (long)y * (64 * 2048);

  const int srow = tid >> 3;
  const int sxor = ((tid & 7) ^ (srow & 7)) * 8;
  const int b = y >> 4, h = y & 15;
  const f32x4 z4 = {0.f, 0.f, 0.f, 0.f};
  short8 ones8;
  #pragma unroll
  for (int j = 0; j < 8; ++j) ones8[j] = (short)0x3F80;

  auto STAGE = [&](int buf, int kt) {
    gl2lds16(Kh + (long)kt * 4096 + srow * 64 + sxor, &Ksm[buf][w * 512]);
    gl2lds16(Vh + kt * 64 + (long)srow * 2048 + sxor, &Vsm[buf][w * 512]);
  };

  for (int pass = 0; pass < 2; ++pass) {
    const int x = pass ? (15 - px) : px;
    const int q0 = x * 128;
    const int qlo = w * 16;

    const float QS = 0.18033688011112042f;
    short8 qf[2];
    {
      short8 r0 = ldv8(Qh + (q0 + qlo + laneRow) * 64 + g * 8);
      short8 r1 = ldv8(Qh + (q0 + qlo + laneRow) * 64 + 32 + g * 8);
      #pragma unroll
      for (int j = 0; j < 8; ++j) {
        qf[0][j] = (short)f2bf(bf2f((unsigned short)r0[j]) * QS);
        qf[1][j] = (short)f2bf(bf2f((unsigned short)r1[j]) * QS);
      }
    }

    float lr[4] = {0.f, 0.f, 0.f, 0.f};
    f32x4 o[4];
    #pragma unroll
    for (int i = 0; i < 4; ++i) o[i] = z4;

    const int nkt = 2 * x + 2;  // always >= 2
    STAGE(0, 0);
    STAGE(1, 1);
    asm volatile("s_waitcnt vmcnt(2)" ::: "memory");
    __builtin_amdgcn_s_barrier();

    int cur = 0, sb = 2;
    for (int kt = 0; kt < nkt; ++kt) {
      if (kt + 2 < nkt) STAGE(sb, kt + 2);

      const int keybase = kt * 64 - q0;
      const bool fullskip = keybase > qlo + 15;

      if (!fullskip) {
        f32x4 sc[4];
        __builtin_amdgcn_s_setprio(1);
        #pragma unroll
        for (int n = 0; n < 4; ++n) {
          const int krow = n * 16 + laneRow;
          short8 b0 = ldv8(&Ksm[cur][krow * 64 + ((g ^ (krow & 7)) * 8)]);
          short8 b1 = ldv8(&Ksm[cur][krow * 64 + (((g + 4) ^ (krow & 7)) * 8)]);
          f32x4 a = mfma16(b0, qf[0], z4);
          sc[n] = mfma16(b1, qf[1], a);
        }
        __builtin_amdgcn_s_setprio(0);

        if (keybase + 63 > qlo) {
          #pragma unroll
          for (int n = 0; n < 4; ++n) {
            const int keyb = keybase + n * 16 + g * 4;
            #pragma unroll
            for (int r = 0; r < 4; ++r)
              if (keyb + r > qlo + laneRow) sc[n][r] = -1e9f;
          }
        }

        #pragma unroll
        for (int n = 0; n < 4; ++n)
          #pragma unroll
          for (int r = 0; r < 4; ++r)
            sc[n][r] = fexp2(sc[n][r]);

        #pragma unroll
        for (int n = 0; n < 4; ++n) {
          uint2 pk;
          pk.x = cvtpk(sc[n][0], sc[n][1]);
          pk.y = cvtpk(sc[n][2], sc[n][3]);
          *(uint2*)&Psm[w][laneRow][n * 16 + g * 4] = pk;
        }
        asm volatile("s_waitcnt lgkmcnt(0)" ::: "memory");

        f32x4 rs = z4;
        #pragma unroll
        for (int kk = 0; kk < 2; ++kk) {
          short8 pf = ldv8(&Psm[w][laneRow][kk * 32 + g * 8]);
          __builtin_amdgcn_s_setprio(1);
          #pragma unroll
          for (int n2 = 0; n2 < 4; ++n2) {
            const int vrow = n2 * 16 + laneRow;
            short8 vf = ldv8(&Vsm[cur][vrow * 64 + (((g + kk * 4) ^ (vrow & 7)) * 8)]);
            o[n2] = mfma16(pf, vf, o[n2]);
          }
          rs = mfma16(pf, ones8, rs);
          __builtin_amdgcn_s_setprio(0);
        }
        #pragma unroll
        for (int r = 0; r < 4; ++r) lr[r] += rs[r];
      }

      if (kt + 2 < nkt) {
        asm volatile("s_waitcnt vmcnt(2)" ::: "memory");
      } else {
        asm volatile("s_waitcnt vmcnt(0)" ::: "memory");
      }
      __builtin_amdgcn_s_barrier();
      cur = (cur == 2) ? 0 : cur + 1;
      sb = (sb == 2) ? 0 : sb + 1;
    }

    #pragma unroll
    for (int n2 = 0; n2 < 4; ++n2) {
      #pragma unroll
      for (int r = 0; r < 4; ++r) {
        float v = o[n2][r] / lr[r];
        long row = (long)b * 2048 + q0 + qlo + g * 4 + r;
        Ao[row * 1024 + h * 64 + n2 * 16 + laneRow] = f2bf(v);
      }
    }
  }
}

// ---------------- launch ----------------
extern "C" void kernel_launch(void* const* d_in, const int* in_sizes, int n_in,
                              void* d_out, int out_size, void* d_ws, size_t ws_size,
                              hipStream_t stream) {
  const float* hs = (const float*)d_in[0];      // [4,2048,1024]
  const float* W_attn = (const float*)d_in[1];  // [1024,3072]
  const float* b_attn = (const float*)d_in[2];  // [3072]
  const float* W_proj = (const float*)d_in[3];  // [1024,1024]
  const float* b_proj = (const float*)d_in[4];  // [1024]
  float* out = (float*)d_out;

  const size_t SZ_HS = 16777216;  // 8192*1024*2
  const size_t SZ_WA = 6291456;   // 3072*1024*2
  const size_t SZ_WP = 2097152;   // 1024*1024*2
  const size_t SZ_T = 16777216;   // Q / K / Vt / Ao each
  if (ws_size < SZ_HS + SZ_WA + SZ_WP + 4 * SZ_T) return;

  char* p = (char*)d_ws;
  unsigned short* hs_bf = (unsigned short*)p; p += SZ_HS;
  unsigned short* WtA = (unsigned short*)p;   p += SZ_WA;
  unsigned short* WtP = (unsigned short*)p;   p += SZ_WP;
  unsigned short* Qb = (unsigned short*)p;    p += SZ_T;
  unsigned short* Kb = (unsigned short*)p;    p += SZ_T;
  unsigned short* Vt = (unsigned short*)p;    p += SZ_T;
  unsigned short* Ao = (unsigned short*)p;    p += SZ_T;

  cast_bf16_kernel<<<8192, 256, 0, stream>>>(hs, hs_bf, 8192 * 1024 / 4);
  transpose_cast_kernel<<<dim3(96, 32), 256, 0, stream>>>(W_attn, WtA, 1024, 3072);
  transpose_cast_kernel<<<dim3(32, 32), 256, 0, stream>>>(W_proj, WtP, 1024, 1024);
  gemm_kernel<0><<<1536, 256, 0, stream>>>(hs_bf, WtA, b_attn, nullptr, Qb, Kb, Vt,
                                           8192, 3072, 1024);
  attn_kernel<<<512, 512, 0, stream>>>(Qb, Kb, Vt, Ao);
  gemm_kernel<1><<<512, 256, 0, stream>>>(Ao, WtP, b_proj, out, nullptr, nullptr, nullptr,
                                          8192, 1024, 1024);
}

// Round 16
// 171.059 us; speedup vs baseline: 2.6560x; 1.0081x over previous
//
#include <hip/hip_runtime.h>
#include <stdint.h>

typedef __attribute__((ext_vector_type(8))) short short8;
typedef __attribute__((ext_vector_type(8))) __bf16 bf16x8v;
typedef __attribute__((ext_vector_type(4))) float f32x4;

#define GLOBAL_AS __attribute__((address_space(1)))
#define LDS_AS __attribute__((address_space(3)))

__device__ __forceinline__ void gl2lds16(const void* g, void* l) {
  __builtin_amdgcn_global_load_lds((const GLOBAL_AS void*)g, (LDS_AS void*)l, 16, 0, 0);
}

__device__ __forceinline__ unsigned short f2bf(float x) {
  unsigned int u = __builtin_bit_cast(unsigned int, x);
  return (unsigned short)((u + 0x7fffu + ((u >> 16) & 1u)) >> 16);
}

__device__ __forceinline__ float bf2f(unsigned short u) {
  unsigned int v = (unsigned int)u << 16;
  return __builtin_bit_cast(float, v);
}

__device__ __forceinline__ unsigned cvtpk(float lo, float hi) {
  unsigned r;
  asm volatile("v_cvt_pk_bf16_f32 %0, %1, %2" : "=v"(r) : "v"(lo), "v"(hi));
  return r;
}

// native 2^x — single v_exp_f32
__device__ __forceinline__ float fexp2(float x) {
  float r;
  asm volatile("v_exp_f32 %0, %1" : "=v"(r) : "v"(x));
  return r;
}

__device__ __forceinline__ short8 ldv8(const unsigned short* p) {
  return *(const short8*)p;
}

// --- MFMA wrapper: SFINAE-hedged against builtin operand type (short8 vs v8bf16) ---
template <typename T>
__device__ __forceinline__ auto mfma_impl(T a, T b, f32x4 c, int)
    -> decltype(__builtin_amdgcn_mfma_f32_16x16x32_bf16(a, b, c, 0, 0, 0)) {
  return __builtin_amdgcn_mfma_f32_16x16x32_bf16(a, b, c, 0, 0, 0);
}
template <typename T>
__device__ __forceinline__ f32x4 mfma_impl(T a, T b, f32x4 c, long) {
  bf16x8v aa = __builtin_bit_cast(bf16x8v, a);
  bf16x8v bb = __builtin_bit_cast(bf16x8v, b);
  return __builtin_amdgcn_mfma_f32_16x16x32_bf16(aa, bb, c, 0, 0, 0);
}
__device__ __forceinline__ f32x4 mfma16(short8 a, short8 b, f32x4 c) {
  return mfma_impl(a, b, c, 0);
}

// ---------------- cast fp32 -> bf16 (vectorized) ----------------
__global__ __launch_bounds__(256) void cast_bf16_kernel(const float* __restrict__ X,
                                                        unsigned short* __restrict__ Y,
                                                        int n4) {
  int i = blockIdx.x * 256 + threadIdx.x;
  if (i >= n4) return;
  const float4 v = ((const float4*)X)[i];
  unsigned long long pk = (unsigned long long)f2bf(v.x)
                        | ((unsigned long long)f2bf(v.y) << 16)
                        | ((unsigned long long)f2bf(v.z) << 32)
                        | ((unsigned long long)f2bf(v.w) << 48);
  ((unsigned long long*)Y)[i] = pk;
}

// ---------------- transpose + cast: W[K][N] fp32 -> Wt[N][K] bf16 ----------------
__global__ __launch_bounds__(256) void transpose_cast_kernel(const float* __restrict__ W,
                                                             unsigned short* __restrict__ Wt,
                                                             int Kd, int Nd) {
  __shared__ unsigned short tile[32][33];
  const int n0 = blockIdx.x * 32, k0 = blockIdx.y * 32;
  const int tx = threadIdx.x & 31, ty = threadIdx.x >> 5;  // 32x8
  #pragma unroll
  for (int i = 0; i < 4; ++i)
    tile[ty + i * 8][tx] = f2bf(W[(long)(k0 + ty + i * 8) * Nd + n0 + tx]);
  __syncthreads();
  #pragma unroll
  for (int i = 0; i < 4; ++i)
    Wt[(long)(n0 + ty + i * 8) * Kd + k0 + tx] = tile[tx][ty + i * 8];
}

// ---------------- QKV GEMM: 256x256, BK=64 (two k-halves), 4-phase/K-tile ------
// 8 waves (2M x 4N), per-wave 128x64 (acc[8][4]). LDS 128KB: per-operand,
// per-k-half double buffer [256][32] (16KB each). Stages go ONLY into the
// next tile's buffers in FIFO order {Ak0,Bk0,Ak1,Bk1}(t+1), one half per
// phase -> only 2 sync points per K-tile, each a counted vmcnt(4)+barrier
// (mid: drains k1(t); end: drains k0(t+1)). Reads XOR-swizzled (R9-verified
// both-sides scheme). XCD decode: 6n x 8m per XCD.
__global__ __launch_bounds__(512, 2) void gemm_qkv256(
    const unsigned short* __restrict__ A,   // [8192][1024] bf16
    const unsigned short* __restrict__ Wt,  // [3072][1024] bf16
    const float* __restrict__ bias,         // [3072]
    unsigned short* __restrict__ Qb,
    unsigned short* __restrict__ Kb,
    unsigned short* __restrict__ Vt) {
  constexpr int K = 1024, NT = 16;
  __shared__ __align__(16) unsigned short Ah[2][2][256 * 32];  // [khalf][buf]
  __shared__ __align__(16) unsigned short Bh[2][2][256 * 32];

  const int tid = threadIdx.x;
  const int w = tid >> 6, l = tid & 63;
  const int bid = blockIdx.x;
  const int xcd = bid & 7, tt = bid >> 3;   // 48 blocks per XCD
  const int xb = (xcd & 1) * 6 + tt % 6;    // 12 n-blocks
  const int yb = (xcd >> 1) * 8 + tt / 6;   // 32 m-blocks
  const int m0 = yb * 256, n0 = xb * 256;

  const int wr = (w >> 2) * 128;            // 0 / 128
  const int wc = (w & 3) * 64;              // 0..192
  const int laneRow = l & 15, laneG = l >> 4;
  const int swz = (laneG ^ (laneRow & 3)) * 8;
  const int aoff = (wr + laneRow) * 32 + swz;
  const int boff = (wc + laneRow) * 32 + swz;

  const unsigned short* Ag = A + (long)m0 * K;
  const unsigned short* Bg = Wt + (long)n0 * K;

  auto STG = [&](unsigned short* dst, const unsigned short* G) {
    #pragma unroll
    for (int i = 0; i < 2; ++i) {
      const int s = i * 512 + tid;
      const int r = s >> 2;
      const int c4 = (s & 3) ^ (r & 3);
      gl2lds16(G + (long)r * K + c4 * 8, dst + (i * 512 + w * 64) * 8);
    }
  };

  const f32x4 z4 = {0.f, 0.f, 0.f, 0.f};
  f32x4 acc[8][4];
  #pragma unroll
  for (int m = 0; m < 8; ++m)
    #pragma unroll
    for (int n = 0; n < 4; ++n) acc[m][n] = z4;

  // prologue: tile0's 4 halves in FIFO order; k0 resident, k1 in flight
  STG(&Ah[0][0][0], Ag + 0);
  STG(&Bh[0][0][0], Bg + 0);
  STG(&Ah[1][0][0], Ag + 32);
  STG(&Bh[1][0][0], Bg + 32);
  asm volatile("s_waitcnt vmcnt(4)" ::: "memory");
  __builtin_amdgcn_s_barrier();

  short8 af[4], bf[4];
  for (int t = 0; t < NT; ++t) {
    const int c = t & 1;
    const int kn = (t + 1) * 64;
    // ---- ph0: B k0 + A m0-3 k0 ; stage Ak0(t+1) ----
    #pragma unroll
    for (int ni = 0; ni < 4; ++ni) bf[ni] = ldv8(&Bh[0][c][boff + ni * 512]);
    #pragma unroll
    for (int mi = 0; mi < 4; ++mi) af[mi] = ldv8(&Ah[0][c][aoff + mi * 512]);
    if (t + 1 < NT) STG(&Ah[0][c ^ 1][0], Ag + kn);
    __builtin_amdgcn_s_setprio(1);
    #pragma unroll
    for (int mi = 0; mi < 4; ++mi)
      #pragma unroll
      for (int ni = 0; ni < 4; ++ni)
        acc[mi][ni] = mfma16(af[mi], bf[ni], acc[mi][ni]);
    __builtin_amdgcn_s_setprio(0);
    // ---- ph1: A m4-7 k0 ; stage Bk0(t+1) ----
    #pragma unroll
    for (int mi = 0; mi < 4; ++mi) af[mi] = ldv8(&Ah[0][c][aoff + 2048 + mi * 512]);
    if (t + 1 < NT) STG(&Bh[0][c ^ 1][0], Bg + kn);
    __builtin_amdgcn_s_setprio(1);
    #pragma unroll
    for (int mi = 0; mi < 4; ++mi)
      #pragma unroll
      for (int ni = 0; ni < 4; ++ni)
        acc[4 + mi][ni] = mfma16(af[mi], bf[ni], acc[4 + mi][ni]);
    __builtin_amdgcn_s_setprio(0);
    // mid-tile: k1(t) must be resident; keep k0(t+1) in flight
    if (t + 1 < NT) {
      asm volatile("s_waitcnt vmcnt(4)" ::: "memory");
    } else {
      asm volatile("s_waitcnt vmcnt(0)" ::: "memory");
    }
    __builtin_amdgcn_s_barrier();
    // ---- ph2: B k1 + A m0-3 k1 ; stage Ak1(t+1) ----
    #pragma unroll
    for (int ni = 0; ni < 4; ++ni) bf[ni] = ldv8(&Bh[1][c][boff + ni * 512]);
    #pragma unroll
    for (int mi = 0; mi < 4; ++mi) af[mi] = ldv8(&Ah[1][c][aoff + mi * 512]);
    if (t + 1 < NT) STG(&Ah[1][c ^ 1][0], Ag + kn + 32);
    __builtin_amdgcn_s_setprio(1);
    #pragma unroll
    for (int mi = 0; mi < 4; ++mi)
      #pragma unroll
      for (int ni = 0; ni < 4; ++ni)
        acc[mi][ni] = mfma16(af[mi], bf[ni], acc[mi][ni]);
    __builtin_amdgcn_s_setprio(0);
    // ---- ph3: A m4-7 k1 ; stage Bk1(t+1) ----
    #pragma unroll
    for (int mi = 0; mi < 4; ++mi) af[mi] = ldv8(&Ah[1][c][aoff + 2048 + mi * 512]);
    if (t + 1 < NT) STG(&Bh[1][c ^ 1][0], Bg + kn + 32);
    __builtin_amdgcn_s_setprio(1);
    #pragma unroll
    for (int mi = 0; mi < 4; ++mi)
      #pragma unroll
      for (int ni = 0; ni < 4; ++ni)
        acc[4 + mi][ni] = mfma16(af[mi], bf[ni], acc[4 + mi][ni]);
    __builtin_amdgcn_s_setprio(0);
    // end-tile: k0(t+1) must be resident; keep k1(t+1) in flight
    if (t + 1 < NT) {
      asm volatile("s_waitcnt vmcnt(4)" ::: "memory");
    } else {
      asm volatile("s_waitcnt vmcnt(0)" ::: "memory");
    }
    __builtin_amdgcn_s_barrier();
  }

  // ---------------- epilogue ----------------
  if (n0 >= 2048) {
    // V: acc reg quad = 4 consecutive tokens at one e -> packed 8B stores
    #pragma unroll
    for (int mi = 0; mi < 8; ++mi) {
      const int row_base = m0 + wr + mi * 16 + laneG * 4;
      #pragma unroll
      for (int ni = 0; ni < 4; ++ni) {
        const int col = n0 + wc + ni * 16 + laneRow;
        const float bv = bias[col];
        const int d = col & 1023;
        const int h = d >> 6, e = d & 63;
        const int bb = row_base >> 11, s = row_base & 2047;
        unsigned long long pk = (unsigned long long)f2bf(acc[mi][ni][0] + bv)
                              | ((unsigned long long)f2bf(acc[mi][ni][1] + bv) << 16)
                              | ((unsigned long long)f2bf(acc[mi][ni][2] + bv) << 32)
                              | ((unsigned long long)f2bf(acc[mi][ni][3] + bv) << 48);
        *(unsigned long long*)(Vt + ((long)((bb * 16 + h) * 64 + e)) * 2048 + s) = pk;
      }
    }
    return;
  }

  // Q/K: per-wave LDS bounce (16x68 f32), coalesced 16B stores
  float* ep = (float*)&Ah[0][0][0] + w * 1088;
  const int c0 = (l & 7) * 8;
  const int rrow = l >> 3;
  const int colg0 = n0 + wc + c0;
  float bv[8];
  #pragma unroll
  for (int j = 0; j < 8; ++j) bv[j] = bias[colg0 + j];
  unsigned short* Tqk = (colg0 >> 10) ? Kb : Qb;
  const int hh = (colg0 & 1023) >> 6;

  #pragma unroll
  for (int mi = 0; mi < 8; ++mi) {
    asm volatile("s_waitcnt lgkmcnt(0)" ::: "memory");
    #pragma unroll
    for (int ni = 0; ni < 4; ++ni)
      #pragma unroll
      for (int r = 0; r < 4; ++r)
        ep[(laneG * 4 + r) * 68 + ni * 16 + laneRow] = acc[mi][ni][r];
    asm volatile("s_waitcnt lgkmcnt(0)" ::: "memory");
    #pragma unroll
    for (int j = 0; j < 2; ++j) {
      const int row = rrow + j * 8;
      f32x4 va = *(const f32x4*)&ep[row * 68 + c0];
      f32x4 vb = *(const f32x4*)&ep[row * 68 + c0 + 4];
      va[0] += bv[0]; va[1] += bv[1]; va[2] += bv[2]; va[3] += bv[3];
      vb[0] += bv[4]; vb[1] += bv[5]; vb[2] += bv[6]; vb[3] += bv[7];
      const int row_g = m0 + wr + mi * 16 + row;
      uint4 pk;
      pk.x = cvtpk(va[0], va[1]);
      pk.y = cvtpk(va[2], va[3]);
      pk.z = cvtpk(vb[0], vb[1]);
      pk.w = cvtpk(vb[2], vb[3]);
      const int bb = row_g >> 11, s = row_g & 2047;
      *(uint4*)(Tqk + ((long)(bb * 16 + hh) * 2048 + s) * 64 + c0) = pk;
    }
  }
}

// ---------------- proj GEMM: 128x128, triple-buffered counted vmcnt(4) -------
__global__ __launch_bounds__(256, 3) void gemm_proj(
    const unsigned short* __restrict__ A,   // [M][K] bf16
    const unsigned short* __restrict__ Wt,  // [N][K] bf16
    const float* __restrict__ bias,         // [N]
    float* __restrict__ Cout,
    int M, int N, int K) {
  __shared__ __align__(16) unsigned short Asm[3][128 * 32];
  __shared__ __align__(16) unsigned short Bsm[3][128 * 32];
  const int tid = threadIdx.x;
  const int w = tid >> 6, l = tid & 63;

  const int bid = blockIdx.x;
  const int xcd = bid & 7, tt = bid >> 3;
  const int xb = tt & 7;
  const int yb = xcd * 8 + (tt >> 3);
  const int m0 = yb * 128, n0 = xb * 128;

  const int wr = (w >> 1) * 64, wc = (w & 1) * 64;
  const int laneRow = l & 15, laneG = l >> 4;

  const f32x4 z4 = {0.f, 0.f, 0.f, 0.f};
  f32x4 acc[4][4];
  #pragma unroll
  for (int m = 0; m < 4; ++m)
    #pragma unroll
    for (int n = 0; n < 4; ++n) acc[m][n] = z4;

  const int srow = tid >> 2;
  const int scol = (tid & 3) * 8;
  const unsigned short* Ag = A + (long)(m0 + srow) * K + scol;
  const unsigned short* Bg = Wt + (long)(n0 + srow) * K + scol;

  const int aoff = (wr + laneRow) * 32 + laneG * 8;
  const int boff = (wc + laneRow) * 32 + laneG * 8;

  auto STAGE = [&](int buf, int kt) {
    gl2lds16(Ag + kt, &Asm[buf][w * 512]);
    gl2lds16(Ag + (long)64 * K + kt, &Asm[buf][2048 + w * 512]);
    gl2lds16(Bg + kt, &Bsm[buf][w * 512]);
    gl2lds16(Bg + (long)64 * K + kt, &Bsm[buf][2048 + w * 512]);
  };

  const int NT = K >> 5;
  STAGE(0, 0);
  STAGE(1, 32);
  asm volatile("s_waitcnt vmcnt(4)" ::: "memory");
  asm volatile("s_barrier" ::: "memory");

  int cur = 0, sb = 2;
  for (int t = 0; t < NT; ++t) {
    if (t + 2 < NT) STAGE(sb, (t + 2) * 32);
    short8 af[4], bfr[4];
    #pragma unroll
    for (int m = 0; m < 4; ++m) af[m] = ldv8(&Asm[cur][aoff + m * 512]);
    #pragma unroll
    for (int n = 0; n < 4; ++n) bfr[n] = ldv8(&Bsm[cur][boff + n * 512]);
    __builtin_amdgcn_s_setprio(1);
    #pragma unroll
    for (int m = 0; m < 4; ++m)
      #pragma unroll
      for (int n = 0; n < 4; ++n)
        acc[m][n] = mfma16(af[m], bfr[n], acc[m][n]);
    __builtin_amdgcn_s_setprio(0);
    if (t + 2 < NT) {
      asm volatile("s_waitcnt vmcnt(4)" ::: "memory");
    } else {
      asm volatile("s_waitcnt vmcnt(0)" ::: "memory");
    }
    asm volatile("s_barrier" ::: "memory");
    cur = (cur == 2) ? 0 : cur + 1;
    sb = (sb == 2) ? 0 : sb + 1;
  }

  // LDS-bounce epilogue -> coalesced f32x4 stores
  float* ep = (float*)&Asm[0][0] + w * 1088;
  const int c0 = (l & 7) * 8;
  const int rrow = l >> 3;
  const int colg0 = n0 + wc + c0;
  float bv[8];
  #pragma unroll
  for (int j = 0; j < 8; ++j) bv[j] = bias[colg0 + j];

  #pragma unroll
  for (int m = 0; m < 4; ++m) {
    asm volatile("s_waitcnt lgkmcnt(0)" ::: "memory");
    #pragma unroll
    for (int n = 0; n < 4; ++n)
      #pragma unroll
      for (int r = 0; r < 4; ++r)
        ep[(laneG * 4 + r) * 68 + n * 16 + laneRow] = acc[m][n][r];
    asm volatile("s_waitcnt lgkmcnt(0)" ::: "memory");
    #pragma unroll
    for (int j = 0; j < 2; ++j) {
      const int row = rrow + j * 8;
      f32x4 va = *(const f32x4*)&ep[row * 68 + c0];
      f32x4 vb = *(const f32x4*)&ep[row * 68 + c0 + 4];
      va[0] += bv[0]; va[1] += bv[1]; va[2] += bv[2]; va[3] += bv[3];
      vb[0] += bv[4]; vb[1] += bv[5]; vb[2] += bv[6]; vb[3] += bv[7];
      const int row_g = m0 + wr + m * 16 + row;
      *(f32x4*)&Cout[(long)row_g * N + colg0] = va;
      *(f32x4*)&Cout[(long)row_g * N + colg0 + 4] = vb;
    }
  }
}

// ---------------- flash attention (causal), bf16 MFMA ----------------
// QBLK=128, 8 waves. Paired tiles px/(15-px), XCD-aware head grouping.
// SWAPPED QK^T -> S^T per lane; P via cvt_pk + b64 writes; no max-shift;
// P = 2^S via single v_exp_f32. Rowsum via mfma(P, ones).
// TRIPLE-buffered K/V with counted vmcnt(2).
__global__ __launch_bounds__(512) void attn_kernel(
    const unsigned short* __restrict__ Qb,   // [B*H][2048][64]
    const unsigned short* __restrict__ Kb,   // [B*H][2048][64]
    const unsigned short* __restrict__ Vt,   // [B*H][64][2048]
    unsigned short* __restrict__ Ao) {       // [B*2048][1024]
  __shared__ __align__(16) unsigned short Ksm[3][64 * 64];
  __shared__ __align__(16) unsigned short Vsm[3][64 * 64];
  __shared__ __align__(16) unsigned short Psm[8][16][72];

  const int tid = threadIdx.x;
  const int w = tid >> 6, l = tid & 63;
  const int bid = blockIdx.x;
  const int px = bid >> 6;                              // 0..7
  const int y = ((bid & 7) << 3) | ((bid >> 3) & 7);    // same-XCD head grouping
  const int laneRow = l & 15, g = l >> 4;
  const unsigned short* Qh = Qb + (long)y * (2048 * 64);
  const unsigned short* Kh = Kb + (long)y * (2048 * 64);
  const unsigned short* Vh = Vt + (long)y * (64 * 2048);

  const int srow = tid >> 3;
  const int sxor = ((tid & 7) ^ (srow & 7)) * 8;
  const int b = y >> 4, h = y & 15;
  const f32x4 z4 = {0.f, 0.f, 0.f, 0.f};
  short8 ones8;
  #pragma unroll
  for (int j = 0; j < 8; ++j) ones8[j] = (short)0x3F80;

  auto STAGE = [&](int buf, int kt) {
    gl2lds16(Kh + (long)kt * 4096 + srow * 64 + sxor, &Ksm[buf][w * 512]);
    gl2lds16(Vh + kt * 64 + (long)srow * 2048 + sxor, &Vsm[buf][w * 512]);
  };

  for (int pass = 0; pass < 2; ++pass) {
    const int x = pass ? (15 - px) : px;
    const int q0 = x * 128;
    const int qlo = w * 16;

    const float QS = 0.18033688011112042f;
    short8 qf[2];
    {
      short8 r0 = ldv8(Qh + (q0 + qlo + laneRow) * 64 + g * 8);
      short8 r1 = ldv8(Qh + (q0 + qlo + laneRow) * 64 + 32 + g * 8);
      #pragma unroll
      for (int j = 0; j < 8; ++j) {
        qf[0][j] = (short)f2bf(bf2f((unsigned short)r0[j]) * QS);
        qf[1][j] = (short)f2bf(bf2f((unsigned short)r1[j]) * QS);
      }
    }

    float lr[4] = {0.f, 0.f, 0.f, 0.f};
    f32x4 o[4];
    #pragma unroll
    for (int i = 0; i < 4; ++i) o[i] = z4;

    const int nkt = 2 * x + 2;  // always >= 2
    STAGE(0, 0);
    STAGE(1, 1);
    asm volatile("s_waitcnt vmcnt(2)" ::: "memory");
    __builtin_amdgcn_s_barrier();

    int cur = 0, sb = 2;
    for (int kt = 0; kt < nkt; ++kt) {
      if (kt + 2 < nkt) STAGE(sb, kt + 2);

      const int keybase = kt * 64 - q0;
      const bool fullskip = keybase > qlo + 15;

      if (!fullskip) {
        f32x4 sc[4];
        __builtin_amdgcn_s_setprio(1);
        #pragma unroll
        for (int n = 0; n < 4; ++n) {
          const int krow = n * 16 + laneRow;
          short8 b0 = ldv8(&Ksm[cur][krow * 64 + ((g ^ (krow & 7)) * 8)]);
          short8 b1 = ldv8(&Ksm[cur][krow * 64 + (((g + 4) ^ (krow & 7)) * 8)]);
          f32x4 a = mfma16(b0, qf[0], z4);
          sc[n] = mfma16(b1, qf[1], a);
        }
        __builtin_amdgcn_s_setprio(0);

        if (keybase + 63 > qlo) {
          #pragma unroll
          for (int n = 0; n < 4; ++n) {
            const int keyb = keybase + n * 16 + g * 4;
            #pragma unroll
            for (int r = 0; r < 4; ++r)
              if (keyb + r > qlo + laneRow) sc[n][r] = -1e9f;
          }
        }

        #pragma unroll
        for (int n = 0; n < 4; ++n)
          #pragma unroll
          for (int r = 0; r < 4; ++r)
            sc[n][r] = fexp2(sc[n][r]);

        #pragma unroll
        for (int n = 0; n < 4; ++n) {
          uint2 pk;
          pk.x = cvtpk(sc[n][0], sc[n][1]);
          pk.y = cvtpk(sc[n][2], sc[n][3]);
          *(uint2*)&Psm[w][laneRow][n * 16 + g * 4] = pk;
        }
        asm volatile("s_waitcnt lgkmcnt(0)" ::: "memory");

        f32x4 rs = z4;
        #pragma unroll
        for (int kk = 0; kk < 2; ++kk) {
          short8 pf = ldv8(&Psm[w][laneRow][kk * 32 + g * 8]);
          __builtin_amdgcn_s_setprio(1);
          #pragma unroll
          for (int n2 = 0; n2 < 4; ++n2) {
            const int vrow = n2 * 16 + laneRow;
            short8 vf = ldv8(&Vsm[cur][vrow * 64 + (((g + kk * 4) ^ (vrow & 7)) * 8)]);
            o[n2] = mfma16(pf, vf, o[n2]);
          }
          rs = mfma16(pf, ones8, rs);
          __builtin_amdgcn_s_setprio(0);
        }
        #pragma unroll
        for (int r = 0; r < 4; ++r) lr[r] += rs[r];
      }

      if (kt + 2 < nkt) {
        asm volatile("s_waitcnt vmcnt(2)" ::: "memory");
      } else {
        asm volatile("s_waitcnt vmcnt(0)" ::: "memory");
      }
      __builtin_amdgcn_s_barrier();
      cur = (cur == 2) ? 0 : cur + 1;
      sb = (sb == 2) ? 0 : sb + 1;
    }

    #pragma unroll
    for (int n2 = 0; n2 < 4; ++n2) {
      #pragma unroll
      for (int r = 0; r < 4; ++r) {
        float v = o[n2][r] / lr[r];
        long row = (long)b * 2048 + q0 + qlo + g * 4 + r;
        Ao[row * 1024 + h * 64 + n2 * 16 + laneRow] = f2bf(v);
      }
    }
  }
}

// ---------------- launch ----------------
extern "C" void kernel_launch(void* const* d_in, const int* in_sizes, int n_in,
                              void* d_out, int out_size, void* d_ws, size_t ws_size,
                              hipStream_t stream) {
  const float* hs = (const float*)d_in[0];      // [4,2048,1024]
  const float* W_attn = (const float*)d_in[1];  // [1024,3072]
  const float* b_attn = (const float*)d_in[2];  // [3072]
  const float* W_proj = (const float*)d_in[3];  // [1024,1024]
  const float* b_proj = (const float*)d_in[4];  // [1024]
  float* out = (float*)d_out;

  const size_t SZ_HS = 16777216;  // 8192*1024*2
  const size_t SZ_WA = 6291456;   // 3072*1024*2
  const size_t SZ_WP = 2097152;   // 1024*1024*2
  const size_t SZ_T = 16777216;   // Q / K / Vt / Ao each
  if (ws_size < SZ_HS + SZ_WA + SZ_WP + 4 * SZ_T) return;

  char* p = (char*)d_ws;
  unsigned short* hs_bf = (unsigned short*)p; p += SZ_HS;
  unsigned short* WtA = (unsigned short*)p;   p += SZ_WA;
  unsigned short* WtP = (unsigned short*)p;   p += SZ_WP;
  unsigned short* Qb = (unsigned short*)p;    p += SZ_T;
  unsigned short* Kb = (unsigned short*)p;    p += SZ_T;
  unsigned short* Vt = (unsigned short*)p;    p += SZ_T;
  unsigned short* Ao = (unsigned short*)p;    p += SZ_T;

  cast_bf16_kernel<<<8192, 256, 0, stream>>>(hs, hs_bf, 8192 * 1024 / 4);
  transpose_cast_kernel<<<dim3(96, 32), 256, 0, stream>>>(W_attn, WtA, 1024, 3072);
  transpose_cast_kernel<<<dim3(32, 32), 256, 0, stream>>>(W_proj, WtP, 1024, 1024);
  gemm_qkv256<<<384, 512, 0, stream>>>(hs_bf, WtA, b_attn, Qb, Kb, Vt);
  attn_kernel<<<512, 512, 0, stream>>>(Qb, Kb, Vt, Ao);
  gemm_proj<<<512, 256, 0, stream>>>(Ao, WtP, b_proj, out, 8192, 1024, 1024);
}

// Round 17
// 165.744 us; speedup vs baseline: 2.7412x; 1.0321x over previous
//
#include <hip/hip_runtime.h>
#include <stdint.h>

typedef __attribute__((ext_vector_type(8))) short short8;
typedef __attribute__((ext_vector_type(8))) __bf16 bf16x8v;
typedef __attribute__((ext_vector_type(4))) float f32x4;

#define GLOBAL_AS __attribute__((address_space(1)))
#define LDS_AS __attribute__((address_space(3)))

__device__ __forceinline__ void gl2lds16(const void* g, void* l) {
  __builtin_amdgcn_global_load_lds((const GLOBAL_AS void*)g, (LDS_AS void*)l, 16, 0, 0);
}

__device__ __forceinline__ unsigned short f2bf(float x) {
  unsigned int u = __builtin_bit_cast(unsigned int, x);
  return (unsigned short)((u + 0x7fffu + ((u >> 16) & 1u)) >> 16);
}

__device__ __forceinline__ float bf2f(unsigned short u) {
  unsigned int v = (unsigned int)u << 16;
  return __builtin_bit_cast(float, v);
}

__device__ __forceinline__ unsigned cvtpk(float lo, float hi) {
  unsigned r;
  asm volatile("v_cvt_pk_bf16_f32 %0, %1, %2" : "=v"(r) : "v"(lo), "v"(hi));
  return r;
}

// native 2^x — single v_exp_f32
__device__ __forceinline__ float fexp2(float x) {
  float r;
  asm volatile("v_exp_f32 %0, %1" : "=v"(r) : "v"(x));
  return r;
}

__device__ __forceinline__ short8 ldv8(const unsigned short* p) {
  return *(const short8*)p;
}

// --- MFMA wrapper: SFINAE-hedged against builtin operand type (short8 vs v8bf16) ---
template <typename T>
__device__ __forceinline__ auto mfma_impl(T a, T b, f32x4 c, int)
    -> decltype(__builtin_amdgcn_mfma_f32_16x16x32_bf16(a, b, c, 0, 0, 0)) {
  return __builtin_amdgcn_mfma_f32_16x16x32_bf16(a, b, c, 0, 0, 0);
}
template <typename T>
__device__ __forceinline__ f32x4 mfma_impl(T a, T b, f32x4 c, long) {
  bf16x8v aa = __builtin_bit_cast(bf16x8v, a);
  bf16x8v bb = __builtin_bit_cast(bf16x8v, b);
  return __builtin_amdgcn_mfma_f32_16x16x32_bf16(aa, bb, c, 0, 0, 0);
}
__device__ __forceinline__ f32x4 mfma16(short8 a, short8 b, f32x4 c) {
  return mfma_impl(a, b, c, 0);
}

// ---------------- cast fp32 -> bf16 (vectorized) ----------------
__global__ __launch_bounds__(256) void cast_bf16_kernel(const float* __restrict__ X,
                                                        unsigned short* __restrict__ Y,
                                                        int n4) {
  int i = blockIdx.x * 256 + threadIdx.x;
  if (i >= n4) return;
  const float4 v = ((const float4*)X)[i];
  unsigned long long pk = (unsigned long long)f2bf(v.x)
                        | ((unsigned long long)f2bf(v.y) << 16)
                        | ((unsigned long long)f2bf(v.z) << 32)
                        | ((unsigned long long)f2bf(v.w) << 48);
  ((unsigned long long*)Y)[i] = pk;
}

// ---------------- transpose + cast: W[K][N] fp32 -> Wt[N][K] bf16 ----------------
__global__ __launch_bounds__(256) void transpose_cast_kernel(const float* __restrict__ W,
                                                             unsigned short* __restrict__ Wt,
                                                             int Kd, int Nd) {
  __shared__ unsigned short tile[32][33];
  const int n0 = blockIdx.x * 32, k0 = blockIdx.y * 32;
  const int tx = threadIdx.x & 31, ty = threadIdx.x >> 5;  // 32x8
  #pragma unroll
  for (int i = 0; i < 4; ++i)
    tile[ty + i * 8][tx] = f2bf(W[(long)(k0 + ty + i * 8) * Nd + n0 + tx]);
  __syncthreads();
  #pragma unroll
  for (int i = 0; i < 4; ++i)
    Wt[(long)(n0 + ty + i * 8) * Kd + k0 + tx] = tile[tx][ty + i * 8];
}

// ---------------- GEMM: C[M,N] = A[M,K] @ Wt[N,K]^T + bias ----------------
// R13 config (measured best: 74.5us gemm0): 128x128 tile, BK=32, TRIPLE-
// buffered counted vmcnt(4), 3 blocks/CU, XCD-aware 1D decode.
// MODE 0: QKV scatter; MODE 1: fp32 out.
template <int MODE>
__global__ __launch_bounds__(256, 3) void gemm_kernel(
    const unsigned short* __restrict__ A,   // [M][K] bf16
    const unsigned short* __restrict__ Wt,  // [N][K] bf16
    const float* __restrict__ bias,         // [N]
    float* __restrict__ Cout,               // MODE1
    unsigned short* __restrict__ Qb,
    unsigned short* __restrict__ Kb,
    unsigned short* __restrict__ Vt,
    int M, int N, int K) {
  __shared__ __align__(16) unsigned short Asm[3][128 * 32];
  __shared__ __align__(16) unsigned short Bsm[3][128 * 32];
  const int tid = threadIdx.x;
  const int w = tid >> 6, l = tid & 63;

  const int bid = blockIdx.x;
  const int xcd = bid & 7, tt = bid >> 3;
  int xb, yb;
  if (MODE == 0) {
    xb = (xcd & 1) * 12 + tt % 12;   // 24 n-blocks
    yb = (xcd >> 1) * 16 + tt / 12;  // 64 m-blocks
  } else {
    xb = tt & 7;                     // 8 n-blocks
    yb = xcd * 8 + (tt >> 3);        // 64 m-blocks
  }
  const int m0 = yb * 128, n0 = xb * 128;

  const int wr = (w >> 1) * 64, wc = (w & 1) * 64;
  const int laneRow = l & 15, laneG = l >> 4;

  const f32x4 z4 = {0.f, 0.f, 0.f, 0.f};
  f32x4 acc[4][4];
  #pragma unroll
  for (int m = 0; m < 4; ++m)
    #pragma unroll
    for (int n = 0; n < 4; ++n) acc[m][n] = z4;

  const int srow = tid >> 2;
  // pre-swizzled global source col (linear LDS dest, swizzled read)
  const int scol = ((tid & 3) ^ (srow & 3)) * 8;
  const unsigned short* Ag = A + (long)(m0 + srow) * K + scol;
  const unsigned short* Bg = Wt + (long)(n0 + srow) * K + scol;

  const int aoff = (wr + laneRow) * 32 + (laneG ^ (laneRow & 3)) * 8;
  const int boff = (wc + laneRow) * 32 + (laneG ^ (laneRow & 3)) * 8;

  auto STAGE = [&](int buf, int kt) {
    gl2lds16(Ag + kt, &Asm[buf][w * 512]);
    gl2lds16(Ag + (long)64 * K + kt, &Asm[buf][2048 + w * 512]);
    gl2lds16(Bg + kt, &Bsm[buf][w * 512]);
    gl2lds16(Bg + (long)64 * K + kt, &Bsm[buf][2048 + w * 512]);
  };

  const int NT = K >> 5;
  STAGE(0, 0);
  STAGE(1, 32);
  asm volatile("s_waitcnt vmcnt(4)" ::: "memory");  // tile0 ready; tile1 in flight
  asm volatile("s_barrier" ::: "memory");

  int cur = 0, sb = 2;
  for (int t = 0; t < NT; ++t) {
    if (t + 2 < NT) STAGE(sb, (t + 2) * 32);
    short8 af[4], bfr[4];
    #pragma unroll
    for (int m = 0; m < 4; ++m) af[m] = ldv8(&Asm[cur][aoff + m * 512]);
    #pragma unroll
    for (int n = 0; n < 4; ++n) bfr[n] = ldv8(&Bsm[cur][boff + n * 512]);
    __builtin_amdgcn_s_setprio(1);
    #pragma unroll
    for (int m = 0; m < 4; ++m)
      #pragma unroll
      for (int n = 0; n < 4; ++n)
        acc[m][n] = mfma16(af[m], bfr[n], acc[m][n]);
    __builtin_amdgcn_s_setprio(0);
    if (t + 2 < NT) {
      asm volatile("s_waitcnt vmcnt(4)" ::: "memory");
    } else {
      asm volatile("s_waitcnt vmcnt(0)" ::: "memory");
    }
    asm volatile("s_barrier" ::: "memory");
    cur = (cur == 2) ? 0 : cur + 1;
    sb = (sb == 2) ? 0 : sb + 1;
  }

  if (MODE == 0 && n0 >= 2048) {
    #pragma unroll
    for (int m = 0; m < 4; ++m) {
      const int row_base = m0 + wr + m * 16 + laneG * 4;
      #pragma unroll
      for (int n = 0; n < 4; ++n) {
        const int col = n0 + wc + n * 16 + laneRow;
        const float bv = bias[col];
        const int d = col & 1023;
        const int h = d >> 6, e = d & 63;
        const int bb = row_base >> 11, s = row_base & 2047;
        unsigned long long pk = (unsigned long long)f2bf(acc[m][n][0] + bv)
                              | ((unsigned long long)f2bf(acc[m][n][1] + bv) << 16)
                              | ((unsigned long long)f2bf(acc[m][n][2] + bv) << 32)
                              | ((unsigned long long)f2bf(acc[m][n][3] + bv) << 48);
        *(unsigned long long*)(Vt + ((long)((bb * 16 + h) * 64 + e)) * 2048 + s) = pk;
      }
    }
    return;
  }

  // LDS-bounce epilogue: per-wave 16x68 f32 region, coalesced 16B stores
  float* ep = (float*)&Asm[0][0] + w * 1088;
  const int c0 = (l & 7) * 8;
  const int rrow = l >> 3;
  const int colg0 = n0 + wc + c0;
  float bv[8];
  #pragma unroll
  for (int j = 0; j < 8; ++j) bv[j] = bias[colg0 + j];
  unsigned short* Tqk = (colg0 >> 10) ? Kb : Qb;
  const int hh = (colg0 & 1023) >> 6, e0 = colg0 & 63;

  #pragma unroll
  for (int m = 0; m < 4; ++m) {
    asm volatile("s_waitcnt lgkmcnt(0)" ::: "memory");
    #pragma unroll
    for (int n = 0; n < 4; ++n)
      #pragma unroll
      for (int r = 0; r < 4; ++r)
        ep[(laneG * 4 + r) * 68 + n * 16 + laneRow] = acc[m][n][r];
    asm volatile("s_waitcnt lgkmcnt(0)" ::: "memory");
    #pragma unroll
    for (int j = 0; j < 2; ++j) {
      const int row = rrow + j * 8;
      f32x4 va = *(const f32x4*)&ep[row * 68 + c0];
      f32x4 vb = *(const f32x4*)&ep[row * 68 + c0 + 4];
      va[0] += bv[0]; va[1] += bv[1]; va[2] += bv[2]; va[3] += bv[3];
      vb[0] += bv[4]; vb[1] += bv[5]; vb[2] += bv[6]; vb[3] += bv[7];
      const int row_g = m0 + wr + m * 16 + row;
      if (MODE == 1) {
        *(f32x4*)&Cout[(long)row_g * N + colg0] = va;
        *(f32x4*)&Cout[(long)row_g * N + colg0 + 4] = vb;
      } else {
        uint4 pk;
        pk.x = cvtpk(va[0], va[1]);
        pk.y = cvtpk(va[2], va[3]);
        pk.z = cvtpk(vb[0], vb[1]);
        pk.w = cvtpk(vb[2], vb[3]);
        const int bb = row_g >> 11, s = row_g & 2047;
        *(uint4*)(Tqk + ((long)(bb * 16 + hh) * 2048 + s) * 64 + e0) = pk;
      }
    }
  }
}

// ---------------- flash attention (causal), bf16 MFMA ----------------
// QBLK=128, 8 waves. Paired tiles px/(15-px), XCD-aware head grouping.
// SWAPPED QK^T -> S^T per lane; P via cvt_pk + b64 writes; no max-shift;
// P = 2^S via single v_exp_f32. Rowsum via mfma(P, ones).
// TRIPLE-buffered K/V, counted vmcnt(2). NEW: split P write/wait — PV kk=0
// waits only on keys 0-31; keys 32-63 written while kk=0's MFMAs run.
__global__ __launch_bounds__(512) void attn_kernel(
    const unsigned short* __restrict__ Qb,   // [B*H][2048][64]
    const unsigned short* __restrict__ Kb,   // [B*H][2048][64]
    const unsigned short* __restrict__ Vt,   // [B*H][64][2048]
    unsigned short* __restrict__ Ao) {       // [B*2048][1024]
  __shared__ __align__(16) unsigned short Ksm[3][64 * 64];
  __shared__ __align__(16) unsigned short Vsm[3][64 * 64];
  __shared__ __align__(16) unsigned short Psm[8][16][72];

  const int tid = threadIdx.x;
  const int w = tid >> 6, l = tid & 63;
  const int bid = blockIdx.x;
  const int px = bid >> 6;                              // 0..7
  const int y = ((bid & 7) << 3) | ((bid >> 3) & 7);    // same-XCD head grouping
  const int laneRow = l & 15, g = l >> 4;
  const unsigned short* Qh = Qb + (long)y * (2048 * 64);
  const unsigned short* Kh = Kb + (long)y * (2048 * 64);
  const unsigned short* Vh = Vt + (long)y * (64 * 2048);

  const int srow = tid >> 3;
  const int sxor = ((tid & 7) ^ (srow & 7)) * 8;
  const int b = y >> 4, h = y & 15;
  const f32x4 z4 = {0.f, 0.f, 0.f, 0.f};
  short8 ones8;
  #pragma unroll
  for (int j = 0; j < 8; ++j) ones8[j] = (short)0x3F80;

  auto STAGE = [&](int buf, int kt) {
    gl2lds16(Kh + (long)kt * 4096 + srow * 64 + sxor, &Ksm[buf][w * 512]);
    gl2lds16(Vh + kt * 64 + (long)srow * 2048 + sxor, &Vsm[buf][w * 512]);
  };

  for (int pass = 0; pass < 2; ++pass) {
    const int x = pass ? (15 - px) : px;
    const int q0 = x * 128;
    const int qlo = w * 16;

    const float QS = 0.18033688011112042f;
    short8 qf[2];
    {
      short8 r0 = ldv8(Qh + (q0 + qlo + laneRow) * 64 + g * 8);
      short8 r1 = ldv8(Qh + (q0 + qlo + laneRow) * 64 + 32 + g * 8);
      #pragma unroll
      for (int j = 0; j < 8; ++j) {
        qf[0][j] = (short)f2bf(bf2f((unsigned short)r0[j]) * QS);
        qf[1][j] = (short)f2bf(bf2f((unsigned short)r1[j]) * QS);
      }
    }

    float lr[4] = {0.f, 0.f, 0.f, 0.f};
    f32x4 o[4];
    #pragma unroll
    for (int i = 0; i < 4; ++i) o[i] = z4;

    const int nkt = 2 * x + 2;  // always >= 2
    STAGE(0, 0);
    STAGE(1, 1);
    asm volatile("s_waitcnt vmcnt(2)" ::: "memory");
    __builtin_amdgcn_s_barrier();

    int cur = 0, sb = 2;
    for (int kt = 0; kt < nkt; ++kt) {
      if (kt + 2 < nkt) STAGE(sb, kt + 2);

      const int keybase = kt * 64 - q0;
      const bool fullskip = keybase > qlo + 15;

      if (!fullskip) {
        f32x4 sc[4];
        __builtin_amdgcn_s_setprio(1);
        #pragma unroll
        for (int n = 0; n < 4; ++n) {
          const int krow = n * 16 + laneRow;
          short8 b0 = ldv8(&Ksm[cur][krow * 64 + ((g ^ (krow & 7)) * 8)]);
          short8 b1 = ldv8(&Ksm[cur][krow * 64 + (((g + 4) ^ (krow & 7)) * 8)]);
          f32x4 a = mfma16(b0, qf[0], z4);
          sc[n] = mfma16(b1, qf[1], a);
        }
        __builtin_amdgcn_s_setprio(0);

        if (keybase + 63 > qlo) {
          #pragma unroll
          for (int n = 0; n < 4; ++n) {
            const int keyb = keybase + n * 16 + g * 4;
            #pragma unroll
            for (int r = 0; r < 4; ++r)
              if (keyb + r > qlo + laneRow) sc[n][r] = -1e9f;
          }
        }

        #pragma unroll
        for (int n = 0; n < 4; ++n)
          #pragma unroll
          for (int r = 0; r < 4; ++r)
            sc[n][r] = fexp2(sc[n][r]);

        // P -> LDS, split halves: keys 0-31 first (n=0,1)
        #pragma unroll
        for (int n = 0; n < 2; ++n) {
          uint2 pk;
          pk.x = cvtpk(sc[n][0], sc[n][1]);
          pk.y = cvtpk(sc[n][2], sc[n][3]);
          *(uint2*)&Psm[w][laneRow][n * 16 + g * 4] = pk;
        }
        asm volatile("s_waitcnt lgkmcnt(0)" ::: "memory");

        f32x4 rs = z4;
        // PV kk=0 reads keys 0-31; issue keys 32-63 writes first, then MFMA
        short8 pf0 = ldv8(&Psm[w][laneRow][g * 8]);
        #pragma unroll
        for (int n = 2; n < 4; ++n) {
          uint2 pk;
          pk.x = cvtpk(sc[n][0], sc[n][1]);
          pk.y = cvtpk(sc[n][2], sc[n][3]);
          *(uint2*)&Psm[w][laneRow][n * 16 + g * 4] = pk;
        }
        __builtin_amdgcn_s_setprio(1);
        #pragma unroll
        for (int n2 = 0; n2 < 4; ++n2) {
          const int vrow = n2 * 16 + laneRow;
          short8 vf = ldv8(&Vsm[cur][vrow * 64 + ((g ^ (vrow & 7)) * 8)]);
          o[n2] = mfma16(pf0, vf, o[n2]);
        }
        rs = mfma16(pf0, ones8, rs);
        __builtin_amdgcn_s_setprio(0);
        asm volatile("s_waitcnt lgkmcnt(0)" ::: "memory");

        short8 pf1 = ldv8(&Psm[w][laneRow][32 + g * 8]);
        __builtin_amdgcn_s_setprio(1);
        #pragma unroll
        for (int n2 = 0; n2 < 4; ++n2) {
          const int vrow = n2 * 16 + laneRow;
          short8 vf = ldv8(&Vsm[cur][vrow * 64 + (((g + 4) ^ (vrow & 7)) * 8)]);
          o[n2] = mfma16(pf1, vf, o[n2]);
        }
        rs = mfma16(pf1, ones8, rs);
        __builtin_amdgcn_s_setprio(0);

        #pragma unroll
        for (int r = 0; r < 4; ++r) lr[r] += rs[r];
      }

      if (kt + 2 < nkt) {
        asm volatile("s_waitcnt vmcnt(2)" ::: "memory");
      } else {
        asm volatile("s_waitcnt vmcnt(0)" ::: "memory");
      }
      __builtin_amdgcn_s_barrier();
      cur = (cur == 2) ? 0 : cur + 1;
      sb = (sb == 2) ? 0 : sb + 1;
    }

    #pragma unroll
    for (int n2 = 0; n2 < 4; ++n2) {
      #pragma unroll
      for (int r = 0; r < 4; ++r) {
        float v = o[n2][r] / lr[r];
        long row = (long)b * 2048 + q0 + qlo + g * 4 + r;
        Ao[row * 1024 + h * 64 + n2 * 16 + laneRow] = f2bf(v);
      }
    }
  }
}

// ---------------- launch ----------------
extern "C" void kernel_launch(void* const* d_in, const int* in_sizes, int n_in,
                              void* d_out, int out_size, void* d_ws, size_t ws_size,
                              hipStream_t stream) {
  const float* hs = (const float*)d_in[0];      // [4,2048,1024]
  const float* W_attn = (const float*)d_in[1];  // [1024,3072]
  const float* b_attn = (const float*)d_in[2];  // [3072]
  const float* W_proj = (const float*)d_in[3];  // [1024,1024]
  const float* b_proj = (const float*)d_in[4];  // [1024]
  float* out = (float*)d_out;

  const size_t SZ_HS = 16777216;  // 8192*1024*2
  const size_t SZ_WA = 6291456;   // 3072*1024*2
  const size_t SZ_WP = 2097152;   // 1024*1024*2
  const size_t SZ_T = 16777216;   // Q / K / Vt / Ao each
  if (ws_size < SZ_HS + SZ_WA + SZ_WP + 4 * SZ_T) return;

  char* p = (char*)d_ws;
  unsigned short* hs_bf = (unsigned short*)p; p += SZ_HS;
  unsigned short* WtA = (unsigned short*)p;   p += SZ_WA;
  unsigned short* WtP = (unsigned short*)p;   p += SZ_WP;
  unsigned short* Qb = (unsigned short*)p;    p += SZ_T;
  unsigned short* Kb = (unsigned short*)p;    p += SZ_T;
  unsigned short* Vt = (unsigned short*)p;    p += SZ_T;
  unsigned short* Ao = (unsigned short*)p;    p += SZ_T;

  cast_bf16_kernel<<<8192, 256, 0, stream>>>(hs, hs_bf, 8192 * 1024 / 4);
  transpose_cast_kernel<<<dim3(96, 32), 256, 0, stream>>>(W_attn, WtA, 1024, 3072);
  transpose_cast_kernel<<<dim3(32, 32), 256, 0, stream>>>(W_proj, WtP, 1024, 1024);
  gemm_kernel<0><<<1536, 256, 0, stream>>>(hs_bf, WtA, b_attn, nullptr, Qb, Kb, Vt,
                                           8192, 3072, 1024);
  attn_kernel<<<512, 512, 0, stream>>>(Qb, Kb, Vt, Ao);
  gemm_kernel<1><<<512, 256, 0, stream>>>(Ao, WtP, b_proj, out, nullptr, nullptr, nullptr,
                                          8192, 1024, 1024);
}